// Round 2
// baseline (2085.319 us; speedup 1.0000x reference)
//
#include <hip/hip_runtime.h>
#include <hip/hip_fp16.h>

typedef _Float16 half8 __attribute__((ext_vector_type(8)));
typedef _Float16 half4 __attribute__((ext_vector_type(4)));
typedef float floatx4 __attribute__((ext_vector_type(4)));

#define TT 512
#define EE 100
#define NBLK 32              // main blocks: 32 batches each (2 streams of 16)
#define WS_NEED ((size_t)64 * TT * 2048 * sizeof(_Float16))

typedef const __attribute__((address_space(1))) void gvoid_t;
typedef __attribute__((address_space(3))) void lvoid_t;

#define MFMA16 __builtin_amdgcn_mfma_f32_16x16x32_f16

__device__ __forceinline__ float sigm(float x) {
    return __builtin_amdgcn_rcpf(1.0f + __expf(-x));
}
__device__ __forceinline__ float tanh_(float x) {
    return __builtin_amdgcn_rcpf(1.0f + __expf(-2.0f * x)) * 2.0f - 1.0f;
}
__device__ __forceinline__ half4 cvt4(float4 v) {
    half4 h; h[0] = (_Float16)v.x; h[1] = (_Float16)v.y; h[2] = (_Float16)v.z; h[3] = (_Float16)v.w;
    return h;
}

// ---- pre-pass: X (fp32 [B][T][100]) -> fragment-ordered fp16 in d_ws ----
// Coalesced transpose via LDS. Block = (batch-group g of 16) x (t-tile of 16).
// Read: per batch, 16 t-rows are CONTIGUOUS (1600 floats) -> perfect float4
// coalescing. Write: per t, [c][m][8] halfs = 4 KB contiguous burst.
// Layout out: xw[g][t][c][m][8], c=k/8, k padded to 128, bias-one at k==100.
extern "C" __global__ void __launch_bounds__(256)
xfrag_prep(const float* __restrict__ X, _Float16* __restrict__ xw)
{
    const int g   = blockIdx.x >> 5;          // batch group 0..63
    const int t0  = (blockIdx.x & 31) << 4;   // t-tile base
    const int tid = threadIdx.x;

    __shared__ __align__(16) _Float16 tile[16][16][120];   // [tt][mm][k] (pad 120)

    // phase 1: coalesced read of 16 batches x (16 t x 100 floats)
    for (int mm = 0; mm < 16; ++mm) {
        const float4* src = (const float4*)(X + ((size_t)(g * 16 + mm) * TT + t0) * EE);
#pragma unroll
        for (int r = 0; r < 2; ++r) {
            const int idx = tid + r * 256;            // 400 float4 per batch
            if (idx < 400) {
                float4 v = src[idx];
                const int tt = idx / 25, kk = idx - 25 * tt;
                *(half4*)&tile[tt][mm][4 * kk] = cvt4(v);
            }
        }
    }
    __syncthreads();

    // phase 2: coalesced write, 16 x 4 KB bursts
    const int c = tid >> 4, mm = tid & 15;
    for (int tt = 0; tt < 16; ++tt) {
        half8 v;
        if (c < 12) {
            v = *(const half8*)&tile[tt][mm][8 * c];
        } else if (c == 12) {
            half4 lo = *(const half4*)&tile[tt][mm][96];
            v[0] = lo[0]; v[1] = lo[1]; v[2] = lo[2]; v[3] = lo[3];
            v[4] = (_Float16)1.0f;                    // bias-one column (k==100)
            v[5] = (_Float16)0.0f; v[6] = (_Float16)0.0f; v[7] = (_Float16)0.0f;
        } else {
#pragma unroll
            for (int j = 0; j < 8; ++j) v[j] = (_Float16)0.0f;
        }
        *(half8*)&xw[((size_t)(g * TT) + t0 + tt) * 2048 + c * 128 + mm * 8] = v;
    }
}

// ---- helpers: one L1 full step / one L2 step (inlined, regs stay live) ----
__device__ __forceinline__ void L1STEP(const _Float16* __restrict__ xslot,
                                       const _Float16* __restrict__ hprev,
                                       _Float16* __restrict__ hout,   // exact half4 ptr
                                       floatx4& c1,
                                       const half8 (&wih)[4][4], const half8 (&whh)[4][4],
                                       int foff)
{
    floatx4 a[4];
#pragma unroll
    for (int gg = 0; gg < 4; ++gg) a[gg] = (floatx4){0.f, 0.f, 0.f, 0.f};
#pragma unroll
    for (int s = 0; s < 4; ++s) {
        half8 bx = *(const half8*)(xslot + s * 512 + foff);
#pragma unroll
        for (int gg = 0; gg < 4; ++gg) a[gg] = MFMA16(wih[gg][s], bx, a[gg], 0, 0, 0);
    }
#pragma unroll
    for (int s = 0; s < 4; ++s) {
        half8 bh = *(const half8*)(hprev + s * 512 + foff);
#pragma unroll
        for (int gg = 0; gg < 4; ++gg) a[gg] = MFMA16(whh[gg][s], bh, a[gg], 0, 0, 0);
    }
    half4 hv;
#pragma unroll
    for (int r = 0; r < 4; ++r) {
        const float iv = sigm(a[0][r]);
        const float fv = sigm(a[1][r]);
        const float gv = tanh_(a[2][r]);
        const float ov = sigm(a[3][r]);
        const float c  = fv * c1[r] + iv * gv;
        c1[r] = c;
        hv[r] = (_Float16)(ov * tanh_(c));
    }
    *(half4*)hout = hv;
}

__device__ __forceinline__ void L2STEP(const _Float16* __restrict__ h1cur,
                                       const _Float16* __restrict__ h2prev,
                                       _Float16* __restrict__ h2out_base,  // + uoff[tau]
                                       const int (&uoff)[2],
                                       float (&c2)[2],
                                       const half8 (&wih)[2][4], const half8 (&whh)[2][2],
                                       const floatx4 (&bias)[2],
                                       int foff)
{
    floatx4 a2[2] = { bias[0], bias[1] };
#pragma unroll
    for (int s = 0; s < 4; ++s) {
        half8 bh = *(const half8*)(h1cur + s * 512 + foff);
        a2[0] = MFMA16(wih[0][s], bh, a2[0], 0, 0, 0);
        a2[1] = MFMA16(wih[1][s], bh, a2[1], 0, 0, 0);
    }
#pragma unroll
    for (int s = 0; s < 2; ++s) {
        half8 bv = *(const half8*)(h2prev + s * 512 + foff);
        a2[0] = MFMA16(whh[0][s], bv, a2[0], 0, 0, 0);
        a2[1] = MFMA16(whh[1][s], bv, a2[1], 0, 0, 0);
    }
#pragma unroll
    for (int tau = 0; tau < 2; ++tau) {
        const float iv = sigm(a2[tau][0]);
        const float fv = sigm(a2[tau][1]);
        const float gv = tanh_(a2[tau][2]);
        const float ov = sigm(a2[tau][3]);
        const float c  = fv * c2[tau] + iv * gv;
        c2[tau] = c;
        h2out_base[uoff[tau]] = (_Float16)(ov * tanh_(c));
    }
}

// ---- main: 32 blocks x 512 threads, block = 2 independent 16-batch streams ----
// Phase 1: L1(A,t) || L2(B,t-1);  Phase 2: L2(A,t) || L1(B,t).
// Every inter-barrier region mixes two independent dependency graphs, so one
// stream's ds_read/MFMA/exp latency chains are filled by the other stream.
template<int USE_WS>
__global__ void __launch_bounds__(512, 1)
lstm_dual(const float* __restrict__ X, const _Float16* __restrict__ xw,
          const float* __restrict__ W1ih, const float* __restrict__ W1hh,
          const float* __restrict__ b1i,  const float* __restrict__ b1h,
          const float* __restrict__ W2ih, const float* __restrict__ W2hh,
          const float* __restrict__ b2i,  const float* __restrict__ b2h,
          const float* __restrict__ fc1w, const float* __restrict__ fc1b,
          const float* __restrict__ fc2w, const float* __restrict__ fc2b,
          float* __restrict__ out)
{
    const int tid  = threadIdx.x;
    const int w    = tid >> 6;
    const int lane = tid & 63;
    const int q    = lane >> 4;
    const int m    = lane & 15;
    const int b0   = blockIdx.x * 32;          // 32 batches per block

    __shared__ __align__(16) _Float16 h1A[2 * 2048];   // 8 KB
    __shared__ __align__(16) _Float16 h1B[2 * 2048];   // 8 KB
    __shared__ __align__(16) _Float16 h2A[2 * 1024];   // 4 KB
    __shared__ __align__(16) _Float16 h2B[2 * 1024];   // 4 KB
    __shared__ __align__(16) _Float16 xbA[2 * 2048];   // 8 KB
    __shared__ __align__(16) _Float16 xbB[2 * 2048];   // 8 KB
    __shared__ float fca[32][32];                      // 4 KB

    // zero-init recurrent state
    for (int i = tid; i < 2 * 2048; i += 512) { h1A[i] = (_Float16)0.0f; h1B[i] = (_Float16)0.0f; }
    for (int i = tid; i < 2 * 1024; i += 512) { h2A[i] = (_Float16)0.0f; h2B[i] = (_Float16)0.0f; }
    if (!USE_WS) {
        for (int i = tid; i < 2 * 2048; i += 512) {
            const int k = i & 2047;                    // bias-one at k==100 column
            const _Float16 v = (k >= 1536 && k < 1664 && (k & 7) == 4) ? (_Float16)1.0f
                                                                       : (_Float16)0.0f;
            xbA[i] = v; xbB[i] = v;
        }
    }

    // ---- weight fragments (shared by both streams) ----
    half8 w1ihf[4][4], w1hhf[4][4], w2ihf[2][4], w2hhf[2][2];
    floatx4 bias2v[2];
#pragma unroll
    for (int g = 0; g < 4; ++g) {
        const int r = g * 128 + 16 * w + m;
        const float bias = b1i[r] + b1h[r];
#pragma unroll
        for (int s = 0; s < 4; ++s) {
            half8 f;
#pragma unroll
            for (int j = 0; j < 8; ++j) {
                const int k = 32 * s + 8 * q + j;
                float v = 0.0f;
                if (k < EE) v = W1ih[r * EE + k];
                else if (k == EE) v = bias;            // pairs with x bias-one column
                f[j] = (_Float16)v;
            }
            w1ihf[g][s] = f;
        }
#pragma unroll
        for (int s = 0; s < 4; ++s) {
            half8 f;
#pragma unroll
            for (int j = 0; j < 8; ++j) f[j] = (_Float16)W1hh[r * 128 + 32 * s + 8 * q + j];
            w1hhf[g][s] = f;
        }
    }
    // L2 gate-interleaved rows: lane (q,m) ends with all 4 gates of unit
    // u = 8w+4tau+q for batch m -> lane-local cell update.
#pragma unroll
    for (int tau = 0; tau < 2; ++tau) {
        const int rr = (m & 3) * 64 + 8 * w + 4 * tau + (m >> 2);
#pragma unroll
        for (int s = 0; s < 4; ++s) {
            half8 f;
#pragma unroll
            for (int j = 0; j < 8; ++j) f[j] = (_Float16)W2ih[rr * 128 + 32 * s + 8 * q + j];
            w2ihf[tau][s] = f;
        }
#pragma unroll
        for (int s = 0; s < 2; ++s) {
            half8 f;
#pragma unroll
            for (int j = 0; j < 8; ++j) f[j] = (_Float16)W2hh[rr * 64 + 32 * s + 8 * q + j];
            w2hhf[tau][s] = f;
        }
        const int uu = 8 * w + 4 * tau + q;
#pragma unroll
        for (int reg = 0; reg < 4; ++reg)
            bias2v[tau][reg] = b2i[reg * 64 + uu] + b2h[reg * 64 + uu];
    }

    // per-thread fragment offsets
    const int foff  = q * 128 + m * 8;
    const int vv    = 2 * w + (q >> 1);
    const int jj    = 4 * (q & 1);
    const int woff1 = (vv >> 2) * 512 + (vv & 3) * 128 + m * 8 + jj;   // h1 write
    int uoff[2];
#pragma unroll
    for (int tau = 0; tau < 2; ++tau) {
        const int u = 8 * w + 4 * tau + q;
        uoff[tau] = (u >> 5) * 512 + ((u >> 3) & 3) * 128 + m * 8 + (u & 7);
    }

    const _Float16* xwbA = xw + (size_t)(2 * blockIdx.x)     * TT * 2048;
    const _Float16* xwbB = xw + (size_t)(2 * blockIdx.x + 1) * TT * 2048;

    // fallback staging setup (reg pipeline, 400 threads per stream)
    int gaddrA = 0, gaddrB = 0, laddr = 0;
    bool xval = false;
    float4 xrA = {0.f, 0.f, 0.f, 0.f}, xrB = {0.f, 0.f, 0.f, 0.f};
    if (!USE_WS) {
        xval = tid < 400;
        const int f = xval ? tid : 0;
        const int n = f / 25, pp = f - 25 * n, e0 = 4 * pp;
        gaddrA = (b0 + n)      * (TT * EE) + e0;
        gaddrB = (b0 + 16 + n) * (TT * EE) + e0;
        const int s = e0 >> 5, qr = (e0 >> 3) & 3, j0 = e0 & 7;
        laddr = ((s * 4 + qr) * 16 + n) * 8 + j0;
    }

    __syncthreads();   // zero-init visible before staging

    if (USE_WS) {      // warmup: x(0),x(1) for both streams
        if (w < 4) {
            __builtin_amdgcn_global_load_lds((gvoid_t*)(xwbA + 0 * 2048 + w * 512 + lane * 8),
                                             (lvoid_t*)(xbA + 0 * 2048 + w * 512), 16, 0, 0);
            __builtin_amdgcn_global_load_lds((gvoid_t*)(xwbA + 1 * 2048 + w * 512 + lane * 8),
                                             (lvoid_t*)(xbA + 1 * 2048 + w * 512), 16, 0, 0);
        } else {
            const int wb = w - 4;
            __builtin_amdgcn_global_load_lds((gvoid_t*)(xwbB + 0 * 2048 + wb * 512 + lane * 8),
                                             (lvoid_t*)(xbB + 0 * 2048 + wb * 512), 16, 0, 0);
            __builtin_amdgcn_global_load_lds((gvoid_t*)(xwbB + 1 * 2048 + wb * 512 + lane * 8),
                                             (lvoid_t*)(xbB + 1 * 2048 + wb * 512), 16, 0, 0);
        }
    } else if (xval) {
        *(half4*)&xbA[0 * 2048 + laddr] = cvt4(*(const float4*)&X[gaddrA + 0 * EE]);
        *(half4*)&xbA[1 * 2048 + laddr] = cvt4(*(const float4*)&X[gaddrA + 1 * EE]);
        *(half4*)&xbB[0 * 2048 + laddr] = cvt4(*(const float4*)&X[gaddrB + 0 * EE]);
        *(half4*)&xbB[1 * 2048 + laddr] = cvt4(*(const float4*)&X[gaddrB + 1 * EE]);
        xrA = *(const float4*)&X[gaddrA + 2 * EE];
        xrB = *(const float4*)&X[gaddrB + 2 * EE];
    }
    __syncthreads();   // staging visible

    floatx4 c1A = {0.f, 0.f, 0.f, 0.f};
    floatx4 c1B = {0.f, 0.f, 0.f, 0.f};
    float c2A[2] = {0.f, 0.f};
    float c2B[2] = {0.f, 0.f};

#pragma unroll 1
    for (int p = 0; p < TT; ++p) {
        const int cur = p & 1, nxt = cur ^ 1;

        // ================= phase 1: L1(A,p)  ||  L2(B,p-1) =================
        L1STEP(xbA + cur * 2048, h1A + nxt * 2048,
               h1A + cur * 2048 + woff1, c1A, w1ihf, w1hhf, foff);
        if (p >= 1) {
            // L2(B, p-1): curB = nxt
            L2STEP(h1B + nxt * 2048, h2B + cur * 1024,
                   h2B + nxt * 1024, uoff, c2B, w2ihf, w2hhf, bias2v, foff);
            if (USE_WS) {
                if (w >= 4) {   // stage xB(p+1) -> xbB[nxt]
                    const int tn = (p + 1 < TT) ? (p + 1) : (TT - 1);
                    const int wb = w - 4;
                    __builtin_amdgcn_global_load_lds((gvoid_t*)(xwbB + (size_t)tn * 2048 + wb * 512 + lane * 8),
                                                     (lvoid_t*)(xbB + nxt * 2048 + wb * 512), 16, 0, 0);
                }
            } else if (xval) {
                *(half4*)&xbB[nxt * 2048 + laddr] = cvt4(xrB);   // xB(p+1)
                const int tn = (p + 2 < TT) ? (p + 2) : (TT - 1);
                xrB = *(const float4*)&X[gaddrB + tn * EE];
            }
        }
        __syncthreads();

        // ================= phase 2: L2(A,p)  ||  L1(B,p) =================
        L2STEP(h1A + cur * 2048, h2A + nxt * 1024,
               h2A + cur * 1024, uoff, c2A, w2ihf, w2hhf, bias2v, foff);
        L1STEP(xbB + cur * 2048, h1B + nxt * 2048,
               h1B + cur * 2048 + woff1, c1B, w1ihf, w1hhf, foff);
        if (USE_WS) {
            if (w < 4) {        // stage xA(p+2) -> xbA[cur]
                const int tn = (p + 2 < TT) ? (p + 2) : (TT - 1);
                __builtin_amdgcn_global_load_lds((gvoid_t*)(xwbA + (size_t)tn * 2048 + w * 512 + lane * 8),
                                                 (lvoid_t*)(xbA + cur * 2048 + w * 512), 16, 0, 0);
            }
        } else if (xval) {
            *(half4*)&xbA[cur * 2048 + laddr] = cvt4(xrA);       // xA(p+2)
            const int tn = (p + 3 < TT) ? (p + 3) : (TT - 1);
            xrA = *(const float4*)&X[gaddrA + tn * EE];
        }
        __syncthreads();
    }

    // epilogue: L2(B, TT-1): curB = (TT-1)&1 = 1
    L2STEP(h1B + 1 * 2048, h2B + 0 * 1024,
           h2B + 1 * 1024, uoff, c2B, w2ihf, w2hhf, bias2v, foff);
    __syncthreads();

    // ---- FC head: 32 batches, finals in h2A[1]/h2B[1] ----
#pragma unroll
    for (int rep = 0; rep < 2; ++rep) {
        const int idx = tid + rep * 512;
        const int nb = idx >> 5, o = idx & 31;
        const _Float16* h2p = (nb < 16 ? h2A : h2B) + 1024 + (nb & 15) * 8;
        float s = fc1b[o];
#pragma unroll
        for (int k = 0; k < 64; ++k)
            s += fc1w[o * 64 + k] * (float)h2p[(k >> 5) * 512 + ((k >> 3) & 3) * 128 + (k & 7)];
        fca[nb][o] = fmaxf(s, 0.0f);
    }
    __syncthreads();
    if (tid < 32) {
        float s = fc2b[0];
#pragma unroll
        for (int k = 0; k < 32; ++k) s += fc2w[k] * fca[tid][k];
        out[b0 + tid] = sigm(s);
    }
}

extern "C" void kernel_launch(void* const* d_in, const int* in_sizes, int n_in,
                              void* d_out, int out_size, void* d_ws, size_t ws_size,
                              hipStream_t stream) {
    const float* X    = (const float*)d_in[0];
    const float* W1ih = (const float*)d_in[1];
    const float* W1hh = (const float*)d_in[2];
    const float* b1i  = (const float*)d_in[3];
    const float* b1h  = (const float*)d_in[4];
    const float* W2ih = (const float*)d_in[5];
    const float* W2hh = (const float*)d_in[6];
    const float* b2i  = (const float*)d_in[7];
    const float* b2h  = (const float*)d_in[8];
    const float* fc1w = (const float*)d_in[9];
    const float* fc1b = (const float*)d_in[10];
    const float* fc2w = (const float*)d_in[11];
    const float* fc2b = (const float*)d_in[12];
    _Float16* xw = (_Float16*)d_ws;

    if (ws_size >= WS_NEED) {
        hipLaunchKernelGGL(xfrag_prep, dim3(2048), dim3(256), 0, stream, X, xw);
        hipLaunchKernelGGL(lstm_dual<1>, dim3(NBLK), dim3(512), 0, stream,
                           X, xw, W1ih, W1hh, b1i, b1h, W2ih, W2hh, b2i, b2h,
                           fc1w, fc1b, fc2w, fc2b, (float*)d_out);
    } else {
        hipLaunchKernelGGL(lstm_dual<0>, dim3(NBLK), dim3(512), 0, stream,
                           X, xw, W1ih, W1hh, b1i, b1h, W2ih, W2hh, b2i, b2h,
                           fc1w, fc1b, fc2w, fc2b, (float*)d_out);
    }
}

// Round 3
// 1129.136 us; speedup vs baseline: 1.8468x; 1.8468x over previous
//
#include <hip/hip_runtime.h>
#include <hip/hip_fp16.h>

typedef _Float16 half8 __attribute__((ext_vector_type(8)));
typedef _Float16 half4 __attribute__((ext_vector_type(4)));
typedef float floatx4 __attribute__((ext_vector_type(4)));

#define TT 512
#define EE 100
#define NBATCH 16
#define NBLK 64
#define WS_NEED ((size_t)NBLK * TT * 2048 * sizeof(_Float16))

typedef const __attribute__((address_space(1))) void gvoid_t;
typedef __attribute__((address_space(3))) void lvoid_t;

#define MFMA16 __builtin_amdgcn_mfma_f32_16x16x32_f16

__device__ __forceinline__ float sigm(float x) {
    return __builtin_amdgcn_rcpf(1.0f + __expf(-x));
}
__device__ __forceinline__ float tanh_(float x) {
    return __builtin_amdgcn_rcpf(1.0f + __expf(-2.0f * x)) * 2.0f - 1.0f;
}
__device__ __forceinline__ half4 cvt4(float4 v) {
    half4 h; h[0] = (_Float16)v.x; h[1] = (_Float16)v.y; h[2] = (_Float16)v.z; h[3] = (_Float16)v.w;
    return h;
}

// ---- pre-pass: X (fp32 [B][T][100]) -> fragment-ordered fp16 in d_ws ----
// Coalesced transpose via LDS. Block = (batch-group g of 16) x (t-tile of 16).
// Layout out: xw[g][t][c][m][8], c=k/8, k padded to 128, bias-one at k==100.
extern "C" __global__ void __launch_bounds__(256)
xfrag_prep(const float* __restrict__ X, _Float16* __restrict__ xw)
{
    const int g   = blockIdx.x >> 5;          // batch group 0..63
    const int t0  = (blockIdx.x & 31) << 4;   // t-tile base
    const int tid = threadIdx.x;

    __shared__ __align__(16) _Float16 tile[16][16][120];   // [tt][mm][k] (pad 120)

    for (int mm = 0; mm < 16; ++mm) {
        const float4* src = (const float4*)(X + ((size_t)(g * 16 + mm) * TT + t0) * EE);
#pragma unroll
        for (int r = 0; r < 2; ++r) {
            const int idx = tid + r * 256;            // 400 float4 per batch
            if (idx < 400) {
                float4 v = src[idx];
                const int tt = idx / 25, kk = idx - 25 * tt;
                *(half4*)&tile[tt][mm][4 * kk] = cvt4(v);
            }
        }
    }
    __syncthreads();

    const int c = tid >> 4, mm = tid & 15;
    for (int tt = 0; tt < 16; ++tt) {
        half8 v;
        if (c < 12) {
            v = *(const half8*)&tile[tt][mm][8 * c];
        } else if (c == 12) {
            half4 lo = *(const half4*)&tile[tt][mm][96];
            v[0] = lo[0]; v[1] = lo[1]; v[2] = lo[2]; v[3] = lo[3];
            v[4] = (_Float16)1.0f;                    // bias-one column (k==100)
            v[5] = (_Float16)0.0f; v[6] = (_Float16)0.0f; v[7] = (_Float16)0.0f;
        } else {
#pragma unroll
            for (int j = 0; j < 8; ++j) v[j] = (_Float16)0.0f;
        }
        *(half8*)&xw[((size_t)(g * TT) + t0 + tt) * 2048 + c * 128 + mm * 8] = v;
    }
}

// ---- main: 64 blocks x 512 threads (8 waves), block = 16 batches, all T ----
// ONE barrier per step; register-neutral vs the non-spilling R0 layout.
// Region 1 (critical): 32 L1 MFMAs, ALL operands in registers (bx,bh carried
//   from previous region 2) -> cell update -> h1 write. Zero LDS reads.
// Region 2 (shadow): issue x(t+2) global_load_lds; BATCHED ds_reads of
//   h1(t) (x4, feeds L2 AND next step's bh), h2(t-1) (x2), x(t+1) (x4 -> bx);
//   12 L2 MFMAs (gate-interleaved, lane-local update); h2 write.
template<int USE_WS>
__global__ void __launch_bounds__(512, 1)
lstm_regc(const float* __restrict__ X, const _Float16* __restrict__ xw,
          const float* __restrict__ W1ih, const float* __restrict__ W1hh,
          const float* __restrict__ b1i,  const float* __restrict__ b1h,
          const float* __restrict__ W2ih, const float* __restrict__ W2hh,
          const float* __restrict__ b2i,  const float* __restrict__ b2h,
          const float* __restrict__ fc1w, const float* __restrict__ fc1b,
          const float* __restrict__ fc2w, const float* __restrict__ fc2b,
          float* __restrict__ out)
{
    const int tid  = threadIdx.x;
    const int w    = tid >> 6;
    const int lane = tid & 63;
    const int q    = lane >> 4;
    const int m    = lane & 15;
    const int b0   = blockIdx.x * NBATCH;

    __shared__ __align__(16) _Float16 h1b[2 * 2048];   // 8 KB (no init needed)
    __shared__ __align__(16) _Float16 h2b[2 * 1024];   // 4 KB
    __shared__ __align__(16) _Float16 xb [2 * 2048];   // 8 KB
    __shared__ float fca[NBATCH][32];

    // zero-init h2 (read at t=0); xb pad/bias zones for fallback
    for (int i = tid; i < 2 * 1024; i += 512) h2b[i] = (_Float16)0.0f;
    if (!USE_WS) {
        for (int i = tid; i < 2 * 2048; i += 512) {
            const int k = i & 2047;     // bias-one at s=3,q=0,j=4 (k==100 col)
            xb[i] = (k >= 1536 && k < 1664 && (k & 7) == 4) ? (_Float16)1.0f
                                                            : (_Float16)0.0f;
        }
    }

    // ---- weight fragments ----
    half8 w1ihf[4][4], w1hhf[4][4], w2ihf[2][4], w2hhf[2][2];
    floatx4 bias2v[2];
#pragma unroll
    for (int g = 0; g < 4; ++g) {
        const int r = g * 128 + 16 * w + m;
        const float bias = b1i[r] + b1h[r];
#pragma unroll
        for (int s = 0; s < 4; ++s) {
            half8 f;
#pragma unroll
            for (int j = 0; j < 8; ++j) {
                const int k = 32 * s + 8 * q + j;
                float v = 0.0f;
                if (k < EE) v = W1ih[r * EE + k];
                else if (k == EE) v = bias;          // pairs with x bias-one column
                f[j] = (_Float16)v;
            }
            w1ihf[g][s] = f;
        }
#pragma unroll
        for (int s = 0; s < 4; ++s) {
            half8 f;
#pragma unroll
            for (int j = 0; j < 8; ++j) f[j] = (_Float16)W1hh[r * 128 + 32 * s + 8 * q + j];
            w1hhf[g][s] = f;
        }
    }
    // L2 gate-interleaved rows: lane (q,m) ends with all 4 gates of unit
    // u = 8w+4tau+q for batch m -> lane-local cell update (proven R1/R2).
#pragma unroll
    for (int tau = 0; tau < 2; ++tau) {
        const int rr = (m & 3) * 64 + 8 * w + 4 * tau + (m >> 2);
#pragma unroll
        for (int s = 0; s < 4; ++s) {
            half8 f;
#pragma unroll
            for (int j = 0; j < 8; ++j) f[j] = (_Float16)W2ih[rr * 128 + 32 * s + 8 * q + j];
            w2ihf[tau][s] = f;
        }
#pragma unroll
        for (int s = 0; s < 2; ++s) {
            half8 f;
#pragma unroll
            for (int j = 0; j < 8; ++j) f[j] = (_Float16)W2hh[rr * 64 + 32 * s + 8 * q + j];
            w2hhf[tau][s] = f;
        }
        const int uu = 8 * w + 4 * tau + q;
#pragma unroll
        for (int reg = 0; reg < 4; ++reg)
            bias2v[tau][reg] = b2i[reg * 64 + uu] + b2h[reg * 64 + uu];
    }

    // per-thread offsets
    const int foff  = q * 128 + m * 8;
    const int vv    = 2 * w + (q >> 1);
    const int jj    = 4 * (q & 1);
    const int woff1 = (vv >> 2) * 512 + (vv & 3) * 128 + m * 8 + jj;   // h1 write
    int uoff[2];
#pragma unroll
    for (int tau = 0; tau < 2; ++tau) {
        const int u = 8 * w + 4 * tau + q;
        uoff[tau] = (u >> 5) * 512 + ((u >> 3) & 3) * 128 + m * 8 + (u & 7);
    }

    const _Float16* xwb = xw + (size_t)blockIdx.x * TT * 2048;

    // fallback staging setup
    int gaddr = 0, laddr = 0;
    bool xval = false;
    float4 xr = {0.f, 0.f, 0.f, 0.f};
    if (!USE_WS) {
        xval = tid < 400;
        const int f = xval ? tid : 0;
        const int n = f / 25, pp = f - 25 * n, e0 = 4 * pp;
        gaddr = (b0 + n) * (TT * EE) + e0;
        const int s = e0 >> 5, qr = (e0 >> 3) & 3, j0 = e0 & 7;
        laddr = ((s * 4 + qr) * 16 + n) * 8 + j0;
    }

    __syncthreads();   // init visible before staging

    if (USE_WS) {      // stage x(0)->xb[0], x(1)->xb[1]
        if (w < 4) {
            __builtin_amdgcn_global_load_lds((gvoid_t*)(xwb + 0 * 2048 + w * 512 + lane * 8),
                                             (lvoid_t*)(xb + 0 * 2048 + w * 512), 16, 0, 0);
            __builtin_amdgcn_global_load_lds((gvoid_t*)(xwb + 1 * 2048 + w * 512 + lane * 8),
                                             (lvoid_t*)(xb + 1 * 2048 + w * 512), 16, 0, 0);
        }
    } else if (xval) {
        *(half4*)&xb[0 * 2048 + laddr] = cvt4(*(const float4*)&X[gaddr + 0 * EE]);
        *(half4*)&xb[1 * 2048 + laddr] = cvt4(*(const float4*)&X[gaddr + 1 * EE]);
        xr = *(const float4*)&X[gaddr + 2 * EE];          // x(2) in regs
    }
    __syncthreads();   // staging visible

    // ---- warmup carries: bx = x(0) fragments, bh = 0 ----
    half8 bx[4], bh[4];
#pragma unroll
    for (int s = 0; s < 4; ++s) {
        bx[s] = *(const half8*)(xb + 0 * 2048 + s * 512 + foff);
#pragma unroll
        for (int j = 0; j < 8; ++j) bh[s][j] = (_Float16)0.0f;
    }

    floatx4 c1 = {0.f, 0.f, 0.f, 0.f};
    float c2[2] = {0.f, 0.f};

#pragma unroll 1
    for (int t = 0; t < TT; ++t) {
        const int cur = t & 1, nxt = cur ^ 1;

        // ---- region 1 (critical, zero LDS reads): L1 gates from registers ----
        {
            floatx4 a[4];
#pragma unroll
            for (int g = 0; g < 4; ++g) a[g] = (floatx4){0.f, 0.f, 0.f, 0.f};
#pragma unroll
            for (int s = 0; s < 4; ++s) {
#pragma unroll
                for (int g = 0; g < 4; ++g) a[g] = MFMA16(w1ihf[g][s], bx[s], a[g], 0, 0, 0);
            }
#pragma unroll
            for (int s = 0; s < 4; ++s) {
#pragma unroll
                for (int g = 0; g < 4; ++g) a[g] = MFMA16(w1hhf[g][s], bh[s], a[g], 0, 0, 0);
            }
            half4 hv;
#pragma unroll
            for (int r = 0; r < 4; ++r) {
                const float iv = sigm(a[0][r]);
                const float fv = sigm(a[1][r]);
                const float gv = tanh_(a[2][r]);
                const float ov = sigm(a[3][r]);
                const float c  = fv * c1[r] + iv * gv;
                c1[r] = c;
                hv[r] = (_Float16)(ov * tanh_(c));
            }
            *(half4*)&h1b[cur * 2048 + woff1] = hv;
        }
        __syncthreads();   // the ONLY barrier per step

        // ---- region 2 (shadow): stage, batched loads, L2 ----
        if (USE_WS) {
            if (w < 4) {   // x(t+2) -> xb[cur]; read at region2(t+1)
                const int tn = (t + 2 < TT) ? (t + 2) : (TT - 1);
                __builtin_amdgcn_global_load_lds((gvoid_t*)(xwb + (size_t)tn * 2048 + w * 512 + lane * 8),
                                                 (lvoid_t*)(xb + cur * 2048 + w * 512), 16, 0, 0);
            }
        } else if (xval) {
            *(half4*)&xb[cur * 2048 + laddr] = cvt4(xr);   // x(t+2)
            const int tn = (t + 3 < TT) ? (t + 3) : (TT - 1);
            xr = *(const float4*)&X[gaddr + tn * EE];
        }

        // batched ds_reads: h1(t) (-> L2 operand AND next bh), h2(t-1), x(t+1) (-> next bx)
        half8 h2f[2];
#pragma unroll
        for (int s = 0; s < 4; ++s) bh[s] = *(const half8*)(h1b + cur * 2048 + s * 512 + foff);
#pragma unroll
        for (int s = 0; s < 2; ++s) h2f[s] = *(const half8*)(h2b + nxt * 1024 + s * 512 + foff);
#pragma unroll
        for (int s = 0; s < 4; ++s) bx[s] = *(const half8*)(xb + nxt * 2048 + s * 512 + foff);

        // L2 gates (2 gate-interleaved tiles per wave)
        floatx4 a2[2] = { bias2v[0], bias2v[1] };
#pragma unroll
        for (int s = 0; s < 4; ++s) {
            a2[0] = MFMA16(w2ihf[0][s], bh[s], a2[0], 0, 0, 0);
            a2[1] = MFMA16(w2ihf[1][s], bh[s], a2[1], 0, 0, 0);
        }
#pragma unroll
        for (int s = 0; s < 2; ++s) {
            a2[0] = MFMA16(w2hhf[0][s], h2f[s], a2[0], 0, 0, 0);
            a2[1] = MFMA16(w2hhf[1][s], h2f[s], a2[1], 0, 0, 0);
        }

        // L2 cell update: lane-local (lane holds all 4 gates of unit u)
#pragma unroll
        for (int tau = 0; tau < 2; ++tau) {
            const float iv = sigm(a2[tau][0]);
            const float fv = sigm(a2[tau][1]);
            const float gv = tanh_(a2[tau][2]);
            const float ov = sigm(a2[tau][3]);
            const float c  = fv * c2[tau] + iv * gv;
            c2[tau] = c;
            h2b[cur * 1024 + uoff[tau]] = (_Float16)(ov * tanh_(c));
        }
        // next iteration's barrier orders h2(t)/h1 reuse
    }
    __syncthreads();

    // ---- FC head (h2 final in h2b[1]) ----
    {
        const int nb = tid >> 5, o = tid & 31;   // 512 = 16 x 32 exactly
        const _Float16* h2p = h2b + 1024 + nb * 8;
        float s = fc1b[o];
#pragma unroll
        for (int k = 0; k < 64; ++k)
            s += fc1w[o * 64 + k] * (float)h2p[(k >> 5) * 512 + ((k >> 3) & 3) * 128 + (k & 7)];
        fca[nb][o] = fmaxf(s, 0.0f);
    }
    __syncthreads();
    if (tid < NBATCH) {
        float s = fc2b[0];
#pragma unroll
        for (int k = 0; k < 32; ++k) s += fc2w[k] * fca[tid][k];
        out[b0 + tid] = sigm(s);
    }
}

extern "C" void kernel_launch(void* const* d_in, const int* in_sizes, int n_in,
                              void* d_out, int out_size, void* d_ws, size_t ws_size,
                              hipStream_t stream) {
    const float* X    = (const float*)d_in[0];
    const float* W1ih = (const float*)d_in[1];
    const float* W1hh = (const float*)d_in[2];
    const float* b1i  = (const float*)d_in[3];
    const float* b1h  = (const float*)d_in[4];
    const float* W2ih = (const float*)d_in[5];
    const float* W2hh = (const float*)d_in[6];
    const float* b2i  = (const float*)d_in[7];
    const float* b2h  = (const float*)d_in[8];
    const float* fc1w = (const float*)d_in[9];
    const float* fc1b = (const float*)d_in[10];
    const float* fc2w = (const float*)d_in[11];
    const float* fc2b = (const float*)d_in[12];
    _Float16* xw = (_Float16*)d_ws;

    if (ws_size >= WS_NEED) {
        hipLaunchKernelGGL(xfrag_prep, dim3(2048), dim3(256), 0, stream, X, xw);
        hipLaunchKernelGGL(lstm_regc<1>, dim3(NBLK), dim3(512), 0, stream,
                           X, xw, W1ih, W1hh, b1i, b1h, W2ih, W2hh, b2i, b2h,
                           fc1w, fc1b, fc2w, fc2b, (float*)d_out);
    } else {
        hipLaunchKernelGGL(lstm_regc<0>, dim3(NBLK), dim3(512), 0, stream,
                           X, xw, W1ih, W1hh, b1i, b1h, W2ih, W2hh, b2i, b2h,
                           fc1w, fc1b, fc2w, fc2b, (float*)d_out);
    }
}

// Round 4
// 948.684 us; speedup vs baseline: 2.1981x; 1.1902x over previous
//
#include <hip/hip_runtime.h>
#include <hip/hip_fp16.h>

typedef _Float16 half8 __attribute__((ext_vector_type(8)));
typedef _Float16 half4 __attribute__((ext_vector_type(4)));
typedef float floatx4 __attribute__((ext_vector_type(4)));

#define TT 512
#define EE 100
#define NBATCH 16
#define NBLK 64

#define MFMA16 __builtin_amdgcn_mfma_f32_16x16x32_f16
#define EXP2   __builtin_amdgcn_exp2f
#define RCP    __builtin_amdgcn_rcpf

// gate pre-scales folded into weight rows/biases:
//   sigmoid rows: y = -a*log2(e)   -> sig = rcp(1+exp2(y))
//   tanh rows:    y = -2a*log2(e)  -> tanh = 2*rcp(1+exp2(y)) - 1
#define S_SIG  (-1.44269504088896340736f)
#define S_TANH (-2.88539008177792681472f)

__device__ __forceinline__ float sigm_slow(float x) {
    return RCP(1.0f + __expf(-x));
}
__device__ __forceinline__ half4 cvt4(float4 v) {
    half4 h; h[0] = (_Float16)v.x; h[1] = (_Float16)v.y; h[2] = (_Float16)v.z; h[3] = (_Float16)v.w;
    return h;
}

// ---- single kernel: 64 blocks x 512 threads (8 waves), block = 16 batches ----
// ONE barrier per step, ONE scheduling region per step:
//   [BAR] ds_read{bh=h1(t-1), h2f=h2(t-2), bx=x(t)}; stage x(t+2)->LDS, load x(t+3)
//   L2MFMA(t-1) ; L1-x MFMA(t) ; L2act(t-1)+h2write   <- VALU interleaves with MFMA
//   L1-hh MFMA(t) ; L1act(t)+h1write ; rotate x slots
// All intra-region LDS read/write sets are disjoint (h1: r[nxt]/w[cur],
// h2: r[cur]/w[nxt], x: r[s0]/w[s2]) so the single top barrier suffices.
__global__ void __launch_bounds__(512, 1)
lstm_fused(const float* __restrict__ X,
           const float* __restrict__ W1ih, const float* __restrict__ W1hh,
           const float* __restrict__ b1i,  const float* __restrict__ b1h,
           const float* __restrict__ W2ih, const float* __restrict__ W2hh,
           const float* __restrict__ b2i,  const float* __restrict__ b2h,
           const float* __restrict__ fc1w, const float* __restrict__ fc1b,
           const float* __restrict__ fc2w, const float* __restrict__ fc2b,
           float* __restrict__ out)
{
    const int tid  = threadIdx.x;
    const int w    = tid >> 6;
    const int lane = tid & 63;
    const int q    = lane >> 4;
    const int m    = lane & 15;
    const int b0   = blockIdx.x * NBATCH;

    __shared__ __align__(16) _Float16 h1b[2 * 2048];   // 8 KB
    __shared__ __align__(16) _Float16 h2b[2 * 1024];   // 4 KB
    __shared__ __align__(16) _Float16 xb [3 * 2048];   // 12 KB (3-slot rotation)
    __shared__ float fca[NBATCH][32];

    // init: xb zeros + bias-one column (k==100 -> s=3,q=0,j=4) in all 3 slots;
    // h1b slot1 = 0 (h1(-1)); h2b slot0 = 0 (h2(-2)).
    for (int i = tid; i < 3 * 2048; i += 512) {
        const int k = i & 2047;
        xb[i] = (k >= 1536 && k < 1664 && (k & 7) == 4) ? (_Float16)1.0f
                                                        : (_Float16)0.0f;
    }
    for (int i = tid; i < 2048; i += 512) h1b[2048 + i] = (_Float16)0.0f;
    for (int i = tid; i < 1024; i += 512) h2b[i] = (_Float16)0.0f;

    // ---- weight fragments (activation scales folded into rows) ----
    half8 w1ihf[4][4], w1hhf[4][4], w2ihf[2][4], w2hhf[2][2];
    floatx4 bias2v[2];
#pragma unroll
    for (int g = 0; g < 4; ++g) {
        const float sg = (g == 2) ? S_TANH : S_SIG;
        const int r = g * 128 + 16 * w + m;
        const float bias = (b1i[r] + b1h[r]) * sg;
#pragma unroll
        for (int s = 0; s < 4; ++s) {
            half8 f;
#pragma unroll
            for (int j = 0; j < 8; ++j) {
                const int k = 32 * s + 8 * q + j;
                float v = 0.0f;
                if (k < EE) v = W1ih[r * EE + k] * sg;
                else if (k == EE) v = bias;          // pairs with x bias-one column
                f[j] = (_Float16)v;
            }
            w1ihf[g][s] = f;
        }
#pragma unroll
        for (int s = 0; s < 4; ++s) {
            half8 f;
#pragma unroll
            for (int j = 0; j < 8; ++j)
                f[j] = (_Float16)(W1hh[r * 128 + 32 * s + 8 * q + j] * sg);
            w1hhf[g][s] = f;
        }
    }
    // L2 gate-interleaved rows: local row m -> gate (m&3), unit 8w+4tau+(m>>2);
    // lane (q,m) ends with all 4 gates of unit u = 8w+4tau+q (lane-local update).
#pragma unroll
    for (int tau = 0; tau < 2; ++tau) {
        const float srow = ((m & 3) == 2) ? S_TANH : S_SIG;
        const int rr = (m & 3) * 64 + 8 * w + 4 * tau + (m >> 2);
#pragma unroll
        for (int s = 0; s < 4; ++s) {
            half8 f;
#pragma unroll
            for (int j = 0; j < 8; ++j)
                f[j] = (_Float16)(W2ih[rr * 128 + 32 * s + 8 * q + j] * srow);
            w2ihf[tau][s] = f;
        }
#pragma unroll
        for (int s = 0; s < 2; ++s) {
            half8 f;
#pragma unroll
            for (int j = 0; j < 8; ++j)
                f[j] = (_Float16)(W2hh[rr * 64 + 32 * s + 8 * q + j] * srow);
            w2hhf[tau][s] = f;
        }
        const int uu = 8 * w + 4 * tau + q;
#pragma unroll
        for (int reg = 0; reg < 4; ++reg)
            bias2v[tau][reg] = (b2i[reg * 64 + uu] + b2h[reg * 64 + uu])
                               * ((reg == 2) ? S_TANH : S_SIG);
    }

    // per-thread offsets
    const int foff  = q * 128 + m * 8;
    const int vv    = 2 * w + (q >> 1);
    const int jj    = 4 * (q & 1);
    const int woff1 = (vv >> 2) * 512 + (vv & 3) * 128 + m * 8 + jj;   // h1 write
    int uoff[2];
#pragma unroll
    for (int tau = 0; tau < 2; ++tau) {
        const int u = 8 * w + 4 * tau + q;
        uoff[tau] = (u >> 5) * 512 + ((u >> 3) & 3) * 128 + m * 8 + (u & 7);
    }

    // x staging (reg pipeline, 400 threads): thread -> (batch n, float4 pp)
    const bool xval = tid < 400;
    const int f    = xval ? tid : 0;
    const int n    = f / 25, pp = f - 25 * n, e0 = 4 * pp;
    const int gaddr = (b0 + n) * (TT * EE) + e0;
    const int ls = e0 >> 5, lq = (e0 >> 3) & 3, lj = e0 & 7;
    const int laddr = ls * 512 + lq * 128 + n * 8 + lj;

    float4 xr = {0.f, 0.f, 0.f, 0.f};
    const float* xp = X + gaddr + 3 * EE;       // points at x(3)
    if (xval) {
        *(half4*)&xb[0 * 2048 + laddr] = cvt4(*(const float4*)&X[gaddr + 0 * EE]); // x(0)
        *(half4*)&xb[1 * 2048 + laddr] = cvt4(*(const float4*)&X[gaddr + 1 * EE]); // x(1)
        xr = *(const float4*)&X[gaddr + 2 * EE];                                   // x(2)
    }

    floatx4 c1 = {0.f, 0.f, 0.f, 0.f};
    float c2[2] = {0.f, 0.f};
    int s0 = 0, s1 = 1, s2 = 2;                 // xb slots: s0 = t mod 3

#pragma unroll 1
    for (int t = 0; t < TT; ++t) {
        const int cur = t & 1, nxt = cur ^ 1;

        __syncthreads();   // orders h1(t-1)/h2(t-2)/x writes before the reads below

        // ---- batched ds_reads ----
        half8 bh[4], bx[4], h2f[2];
#pragma unroll
        for (int s = 0; s < 4; ++s) bh[s] = *(const half8*)(h1b + nxt * 2048 + s * 512 + foff);
#pragma unroll
        for (int s = 0; s < 2; ++s) h2f[s] = *(const half8*)(h2b + cur * 1024 + s * 512 + foff);
#pragma unroll
        for (int s = 0; s < 4; ++s) bx[s] = *(const half8*)(xb + s0 * 2048 + s * 512 + foff);

        // ---- stage x(t+2) -> slot s2; issue load of x(t+3) ----
        if (xval) {
            *(half4*)&xb[s2 * 2048 + laddr] = cvt4(xr);
            xr = *(const float4*)xp;
            if (t < TT - 4) xp += EE;
        }

        // ---- L2 MFMAs for step t-1 ----
        floatx4 a2[2];
        if (t == 0) { a2[0] = (floatx4){0.f,0.f,0.f,0.f}; a2[1] = (floatx4){0.f,0.f,0.f,0.f}; }
        else        { a2[0] = bias2v[0]; a2[1] = bias2v[1]; }
#pragma unroll
        for (int s = 0; s < 4; ++s) {
            a2[0] = MFMA16(w2ihf[0][s], bh[s], a2[0], 0, 0, 0);
            a2[1] = MFMA16(w2ihf[1][s], bh[s], a2[1], 0, 0, 0);
        }
#pragma unroll
        for (int s = 0; s < 2; ++s) {
            a2[0] = MFMA16(w2hhf[0][s], h2f[s], a2[0], 0, 0, 0);
            a2[1] = MFMA16(w2hhf[1][s], h2f[s], a2[1], 0, 0, 0);
        }

        // ---- L1 x-part MFMAs (independent of bh chain) ----
        floatx4 a[4];
#pragma unroll
        for (int g = 0; g < 4; ++g) a[g] = (floatx4){0.f, 0.f, 0.f, 0.f};
#pragma unroll
        for (int s = 0; s < 4; ++s) {
#pragma unroll
            for (int g = 0; g < 4; ++g) a[g] = MFMA16(w1ihf[g][s], bx[s], a[g], 0, 0, 0);
        }

        // ---- L2 act (step t-1): VALU, interleaves with MFMA pipe ----
#pragma unroll
        for (int tau = 0; tau < 2; ++tau) {
            const float iv = RCP(1.0f + EXP2(a2[tau][0]));
            const float fv = RCP(1.0f + EXP2(a2[tau][1]));
            const float gv = fmaf(2.0f, RCP(1.0f + EXP2(a2[tau][2])), -1.0f);
            const float ov = RCP(1.0f + EXP2(a2[tau][3]));
            const float c  = fv * c2[tau] + iv * gv;
            c2[tau] = c;
            const float th = fmaf(2.0f, RCP(1.0f + EXP2(c * S_TANH)), -1.0f);
            h2b[nxt * 1024 + uoff[tau]] = (_Float16)(ov * th);
        }

        // ---- L1 hh-part MFMAs ----
#pragma unroll
        for (int s = 0; s < 4; ++s) {
#pragma unroll
            for (int g = 0; g < 4; ++g) a[g] = MFMA16(w1hhf[g][s], bh[s], a[g], 0, 0, 0);
        }

        // ---- L1 act (step t) -> h1 write ----
        {
            half4 hv;
#pragma unroll
            for (int r = 0; r < 4; ++r) {
                const float iv = RCP(1.0f + EXP2(a[0][r]));
                const float fv = RCP(1.0f + EXP2(a[1][r]));
                const float gv = fmaf(2.0f, RCP(1.0f + EXP2(a[2][r])), -1.0f);
                const float ov = RCP(1.0f + EXP2(a[3][r]));
                const float c  = fv * c1[r] + iv * gv;
                c1[r] = c;
                const float th = fmaf(2.0f, RCP(1.0f + EXP2(c * S_TANH)), -1.0f);
                hv[r] = (_Float16)(ov * th);
            }
            *(half4*)&h1b[cur * 2048 + woff1] = hv;
        }

        // rotate x slots
        const int st = s0; s0 = s1; s1 = s2; s2 = st;
    }

    // ---- epilogue: final L2 step (t = TT-1) ----
    __syncthreads();
    {
        half8 bh[4], h2f[2];
#pragma unroll
        for (int s = 0; s < 4; ++s) bh[s] = *(const half8*)(h1b + 1 * 2048 + s * 512 + foff);
#pragma unroll
        for (int s = 0; s < 2; ++s) h2f[s] = *(const half8*)(h2b + 0 * 1024 + s * 512 + foff);
        floatx4 a2[2] = { bias2v[0], bias2v[1] };
#pragma unroll
        for (int s = 0; s < 4; ++s) {
            a2[0] = MFMA16(w2ihf[0][s], bh[s], a2[0], 0, 0, 0);
            a2[1] = MFMA16(w2ihf[1][s], bh[s], a2[1], 0, 0, 0);
        }
#pragma unroll
        for (int s = 0; s < 2; ++s) {
            a2[0] = MFMA16(w2hhf[0][s], h2f[s], a2[0], 0, 0, 0);
            a2[1] = MFMA16(w2hhf[1][s], h2f[s], a2[1], 0, 0, 0);
        }
#pragma unroll
        for (int tau = 0; tau < 2; ++tau) {
            const float iv = RCP(1.0f + EXP2(a2[tau][0]));
            const float fv = RCP(1.0f + EXP2(a2[tau][1]));
            const float gv = fmaf(2.0f, RCP(1.0f + EXP2(a2[tau][2])), -1.0f);
            const float ov = RCP(1.0f + EXP2(a2[tau][3]));
            const float c  = fv * c2[tau] + iv * gv;
            c2[tau] = c;
            const float th = fmaf(2.0f, RCP(1.0f + EXP2(c * S_TANH)), -1.0f);
            h2b[1 * 1024 + uoff[tau]] = (_Float16)(ov * th);
        }
    }
    __syncthreads();

    // ---- FC head (h2 final in slot 1) ----
    {
        const int nb = tid >> 5, o = tid & 31;   // 512 = 16 x 32 exactly
        const _Float16* h2p = h2b + 1024 + nb * 8;
        float s = fc1b[o];
#pragma unroll
        for (int k = 0; k < 64; ++k)
            s += fc1w[o * 64 + k] * (float)h2p[(k >> 5) * 512 + ((k >> 3) & 3) * 128 + (k & 7)];
        fca[nb][o] = fmaxf(s, 0.0f);
    }
    __syncthreads();
    if (tid < NBATCH) {
        float s = fc2b[0];
#pragma unroll
        for (int k = 0; k < 32; ++k) s += fc2w[k] * fca[tid][k];
        out[b0 + tid] = sigm_slow(s);
    }
}

extern "C" void kernel_launch(void* const* d_in, const int* in_sizes, int n_in,
                              void* d_out, int out_size, void* d_ws, size_t ws_size,
                              hipStream_t stream) {
    const float* X    = (const float*)d_in[0];
    const float* W1ih = (const float*)d_in[1];
    const float* W1hh = (const float*)d_in[2];
    const float* b1i  = (const float*)d_in[3];
    const float* b1h  = (const float*)d_in[4];
    const float* W2ih = (const float*)d_in[5];
    const float* W2hh = (const float*)d_in[6];
    const float* b2i  = (const float*)d_in[7];
    const float* b2h  = (const float*)d_in[8];
    const float* fc1w = (const float*)d_in[9];
    const float* fc1b = (const float*)d_in[10];
    const float* fc2w = (const float*)d_in[11];
    const float* fc2b = (const float*)d_in[12];

    hipLaunchKernelGGL(lstm_fused, dim3(NBLK), dim3(512), 0, stream,
                       X, W1ih, W1hh, b1i, b1h, W2ih, W2hh, b2i, b2h,
                       fc1w, fc1b, fc2w, fc2b, (float*)d_out);
}